// Round 8
// baseline (250.380 us; speedup 1.0000x reference)
//
#include <hip/hip_runtime.h>

typedef unsigned short ushort_t;
typedef __attribute__((ext_vector_type(8))) short bf16x8;     // 8 bf16 in 4 VGPRs
typedef __attribute__((ext_vector_type(2))) float f32x2;
typedef __attribute__((ext_vector_type(4))) float f32x4;
typedef __attribute__((ext_vector_type(16))) float f32x16;

__device__ __forceinline__ unsigned short f2bf(float f) {
    union { float f; unsigned u; } v; v.f = f;
    unsigned r = v.u + 0x7FFFu + ((v.u >> 16) & 1u);   // RNE
    return (unsigned short)(r >> 16);
}

// v_cvt_pk_bf16_f32: lo=RNE(a), hi=RNE(b) — bit-identical to f2bf, 1 inst / 2 elems
__device__ __forceinline__ unsigned cvt_pk_bf16(float a, float b) {
    unsigned r;
    asm("v_cvt_pk_bf16_f32 %0, %1, %2" : "=v"(r) : "v"(a), "v"(b));
    return r;
}

// ================= weight prep, fragment-major, coalesced writes =================
// B-fragment layout for v_mfma_f32_32x32x16_bf16: lane = khalf*32 + r32 holds
// W[ngrp*32 + r32][kfrag*16 + khalf*8 .. +8).  Stored as
//   Wf[(ngrp*KFRAGS + kfrag)*512 + lane*8 + e]
// W1eff folds the 3x3 conv into fc1 (p indexes the 28x28 input, zero-padded to 832).
// Conv-fold taps are branch-free: clamped addresses + zeroed weights -> 9 independent loads.
__global__ __launch_bounds__(256) void prep_w(const float* __restrict__ fc1_w,
                                              const float* __restrict__ cw,
                                              const float* __restrict__ fc2_w,
                                              const float* __restrict__ out_w,
                                              ushort_t* __restrict__ W1,
                                              ushort_t* __restrict__ W2,
                                              ushort_t* __restrict__ W3) {
    const int idx = blockIdx.x * 256 + threadIdx.x;
    // ---- W1f: 16 ngrps x 52 kfrags x 512 = 425984 elements ----
    if (idx < 425984) {
        const int ngrp = idx / 26624;              // 52*512
        const int kfrag = (idx % 26624) >> 9;
        const int li = idx & 511;
        const int lane = li >> 3, e = li & 7;
        const int n = ngrp * 32 + (lane & 31);
        const int p = kfrag * 16 + (lane >> 5) * 8 + e;
        float acc = 0.f;
        if (p < 784) {
            const int pr = p / 28, pc = p % 28;
            const float* frow = &fc1_w[n * 676];
#pragma unroll
            for (int dr = 0; dr < 3; ++dr) {
                const int r = pr - dr;
                const bool rok = (unsigned)r < 26u;
                const int rc = rok ? r : 0;
#pragma unroll
                for (int dc = 0; dc < 3; ++dc) {
                    const int c = pc - dc;
                    const bool cok = (unsigned)c < 26u;
                    const int cc = cok ? c : 0;
                    const float w = (rok && cok) ? cw[dr * 3 + dc] : 0.f;
                    acc += w * frow[rc * 26 + cc];     // always-safe address, weight 0 if pad
                }
            }
        }
        W1[idx] = f2bf(acc);
    }
    // ---- W2f: 16 ngrps x 32 kfrags x 512 = 262144 ----
    if (idx < 262144) {
        const int ngrp = idx / 16384;              // 32*512
        const int kfrag = (idx % 16384) >> 9;
        const int li = idx & 511;
        const int lane = li >> 3, e = li & 7;
        const int n = ngrp * 32 + (lane & 31);
        const int p = kfrag * 16 + (lane >> 5) * 8 + e;
        W2[idx] = f2bf(fc2_w[n * 512 + p]);
    }
    if (idx < 16 * 512)  W3[idx] = (idx < 10 * 512) ? f2bf(out_w[idx]) : (ushort_t)0;
}

// ================= fully-fused network, v11: 16-AGPR accumulator, no spill =================
// 1024 blocks x 32 batch rows, 1024 threads (16 waves), launch_bounds(1024,8): 2 blocks/CU,
// 8 waves/SIMD. Key: block output 32x512 f32 = 16 f32/thread -> acc = ONE f32x16 (16 AGPR),
// leaving ~48 arch VGPRs inside the 64-reg budget — enough to burst-load all 4 W fragments
// + 4 A fragments per K-step ahead of the MFMAs with ZERO scratch spill (v9/v10 spilled
// ~40MB/launch because M=64 forced 32 AGPR + transients into 32 arch regs).
// Per ksub per wave: 1 coalesced 1KB W load (L2) + 1 ds_read_b128 + 1 MFMA.
// x staging: 2 f32/thread -> 1 packed cvt -> 1 dword LDS write (conflict-free).
// LDS: xs0 [32][64] 4KB dbuf (buffer B aliases first 4KB of hs) + hs [32][512] 32KB = 36KB.
__global__ __launch_bounds__(1024, 8) void mega11(const float* __restrict__ x,
                                                  const ushort_t* __restrict__ W1,
                                                  const ushort_t* __restrict__ W2,
                                                  const ushort_t* __restrict__ W3,
                                                  const float* __restrict__ b1,
                                                  const float* __restrict__ b2,
                                                  const float* __restrict__ ob,
                                                  float* __restrict__ out) {
    extern __shared__ ushort_t smem[];
    ushort_t* xs0 = smem;                // [32][64]   4 KB  x buffer A (seg-swizzled)
    ushort_t* hs  = smem + 2048;         // [32][512] 32 KB h1/h2 tile; first 4KB = x buffer B

    const int tid = threadIdx.x;
    const int wave = tid >> 6, lane = tid & 63;
    const int r32 = lane & 31, khalf = lane >> 5;
    const int xrow = tid >> 5, xc2 = (tid & 31) * 2;    // x staging: 32 rows x 32 lanes x 2 cols
    const int m0 = blockIdx.x * 32;
    const size_t ng = wave;                             // this wave's n-group (n = wave*32+r32)

    // per-thread staging addresses (loop-invariant)
    const float* xgp = &x[(size_t)(m0 + xrow) * 784 + xc2];
    const int xldso = xrow * 64 + (((xc2 >> 3) ^ (xrow & 7)) * 8) + (xc2 & 7);

    f32x16 acc;                                         // 16 AGPRs
#pragma unroll
    for (int e = 0; e < 16; ++e) acc[e] = 0.f;

    f32x2 xv;                                           // staged x (2 VGPR)
    auto load_x = [&](int ks) {
        const int gc = ks * 64 + xc2;
        if (gc < 784) {
            xv = __builtin_nontemporal_load((const f32x2*)(xgp + ks * 64));
        } else {
            xv = (f32x2){0.f, 0.f};
        }
    };
    auto write_x = [&](ushort_t* buf) {                 // one dword LDS write, conflict-free
        *(unsigned*)&buf[xldso] = cvt_pk_bf16(xv.x, xv.y);
    };

    // h-epilogue: bias+relu -> hs (A-layout, seg' = seg ^ (m&7)); cols = this wave's 32 n
    auto write_h = [&](const float* __restrict__ bias) {
        const int n = wave * 32 + r32;
        const float bb = bias[n];
        const int nseg = n >> 3, nrem = n & 7;
#pragma unroll
        for (int reg = 0; reg < 16; ++reg) {
            const int m = 4 * khalf + (reg & 3) + 8 * (reg >> 2);      // 0..31
            hs[m * 512 + ((nseg ^ (m & 7)) * 8) + nrem] = f2bf(fmaxf(acc[reg] + bb, 0.f));
        }
    };

    load_x(0);
    write_x(xs0);
    __syncthreads();

    // ---------------- phase 1: K = 832, 12 full steps of BK=64, 1 barrier/step ----------------
    for (int ks = 0; ks < 12; ++ks) {
        load_x(ks + 1);                                 // next x flies under the step
        const ushort_t* bufp = (ks & 1) ? hs : xs0;
        const ushort_t* wp = &W1[(ng * 52 + ks * 4) * 512 + lane * 8];
        const int ro = r32 * 64, sw = r32 & 7;
        // burst: all 4 W fragments (L2) + all 4 A fragments (LDS) issued before the MFMAs
        const bf16x8 bw0 = *(const bf16x8*)(wp);
        const bf16x8 bw1 = *(const bf16x8*)(wp + 512);
        const bf16x8 bw2 = *(const bf16x8*)(wp + 1024);
        const bf16x8 bw3 = *(const bf16x8*)(wp + 1536);
        const bf16x8 a0 = *(const bf16x8*)&bufp[ro + (((0 + khalf) ^ sw) * 8)];
        const bf16x8 a1 = *(const bf16x8*)&bufp[ro + (((2 + khalf) ^ sw) * 8)];
        const bf16x8 a2 = *(const bf16x8*)&bufp[ro + (((4 + khalf) ^ sw) * 8)];
        const bf16x8 a3 = *(const bf16x8*)&bufp[ro + (((6 + khalf) ^ sw) * 8)];
        __builtin_amdgcn_s_setprio(1);
        acc = __builtin_amdgcn_mfma_f32_32x32x16_bf16(a0, bw0, acc, 0, 0, 0);
        acc = __builtin_amdgcn_mfma_f32_32x32x16_bf16(a1, bw1, acc, 0, 0, 0);
        acc = __builtin_amdgcn_mfma_f32_32x32x16_bf16(a2, bw2, acc, 0, 0, 0);
        acc = __builtin_amdgcn_mfma_f32_32x32x16_bf16(a3, bw3, acc, 0, 0, 0);
        __builtin_amdgcn_s_setprio(0);
        write_x((ks & 1) ? xs0 : hs);                   // fill the other buffer
        __syncthreads();
    }
    // ---- step 12: only kfrag 48 is nonzero (k 768..783 real; 784..831 is zero pad) ----
    {
        const ushort_t* bufp = xs0;                     // ks=12 even -> buffer A
        const bf16x8 bw = *(const bf16x8*)&W1[(ng * 52 + 48) * 512 + lane * 8];
        const bf16x8 a0 = *(const bf16x8*)&bufp[r32 * 64 + ((khalf ^ (r32 & 7)) * 8)];
        __builtin_amdgcn_s_setprio(1);
        acc = __builtin_amdgcn_mfma_f32_32x32x16_bf16(a0, bw, acc, 0, 0, 0);
        __builtin_amdgcn_s_setprio(0);
    }
    // no barrier needed: step-12 read xs0 only; h1 writes touch hs, whose last readers
    // (step 11 x-alias reads) finished before the ks=11 barrier.

    // ---- h1 = relu(acc + b1) -> hs ----
    write_h(b1);
#pragma unroll
    for (int e = 0; e < 16; ++e) acc[e] = 0.f;
    __syncthreads();

    // ---------------- phase 2: K = 512, 8 steps, no intra-phase barriers ----------------
    for (int ks = 0; ks < 8; ++ks) {
        const ushort_t* wp = &W2[(ng * 32 + ks * 4) * 512 + lane * 8];
        const int ro = r32 * 512, sw = r32 & 7, hq0 = ks * 8 + khalf;
        const bf16x8 bw0 = *(const bf16x8*)(wp);
        const bf16x8 bw1 = *(const bf16x8*)(wp + 512);
        const bf16x8 bw2 = *(const bf16x8*)(wp + 1024);
        const bf16x8 bw3 = *(const bf16x8*)(wp + 1536);
        const bf16x8 a0 = *(const bf16x8*)&hs[ro + (((hq0 + 0) ^ sw) * 8)];
        const bf16x8 a1 = *(const bf16x8*)&hs[ro + (((hq0 + 2) ^ sw) * 8)];
        const bf16x8 a2 = *(const bf16x8*)&hs[ro + (((hq0 + 4) ^ sw) * 8)];
        const bf16x8 a3 = *(const bf16x8*)&hs[ro + (((hq0 + 6) ^ sw) * 8)];
        __builtin_amdgcn_s_setprio(1);
        acc = __builtin_amdgcn_mfma_f32_32x32x16_bf16(a0, bw0, acc, 0, 0, 0);
        acc = __builtin_amdgcn_mfma_f32_32x32x16_bf16(a1, bw1, acc, 0, 0, 0);
        acc = __builtin_amdgcn_mfma_f32_32x32x16_bf16(a2, bw2, acc, 0, 0, 0);
        acc = __builtin_amdgcn_mfma_f32_32x32x16_bf16(a3, bw3, acc, 0, 0, 0);
        __builtin_amdgcn_s_setprio(0);
    }
    __syncthreads();                                    // all hs(h1) reads done

    // ---- h2 = relu(acc + b2) -> hs ----
    write_h(b2);
    __syncthreads();

    // ---------------- head: waves 0..1 -> 16 rows each, K=512, direct stores ----------------
    if (wave < 2) {
        const int quad = lane >> 4, l16 = lane & 15;
        const int row = wave * 16 + l16;
        f32x4 hacc = {0.f, 0.f, 0.f, 0.f};
#pragma unroll
        for (int ks = 0; ks < 16; ++ks) {
            const int seg = 4 * ks + quad;
            const bf16x8 a = *(const bf16x8*)&hs[row * 512 + ((seg ^ (row & 7)) * 8)];
            const bf16x8 b = *(const bf16x8*)&W3[l16 * 512 + ks * 32 + quad * 8];
            hacc = __builtin_amdgcn_mfma_f32_16x16x32_bf16(a, b, hacc, 0, 0, 0);
        }
        if (l16 < 10) {
            const float bb = ob[l16];
#pragma unroll
            for (int r = 0; r < 4; ++r)
                out[(size_t)(m0 + wave * 16 + quad * 4 + r) * 10 + l16] = hacc[r] + bb;
        }
    }
}

extern "C" void kernel_launch(void* const* d_in, const int* in_sizes, int n_in,
                              void* d_out, int out_size, void* d_ws, size_t ws_size,
                              hipStream_t stream) {
    const float* x      = (const float*)d_in[0];
    const float* conv_w = (const float*)d_in[1];
    const float* fc1_w  = (const float*)d_in[2];
    const float* fc1_b  = (const float*)d_in[3];
    const float* fc2_w  = (const float*)d_in[4];
    const float* fc2_b  = (const float*)d_in[5];
    const float* out_w  = (const float*)d_in[6];
    const float* out_b  = (const float*)d_in[7];
    float* out = (float*)d_out;

    // workspace: W1f | W2f | W3 (≈1.4 MB total), fragment-major layouts
    ushort_t* W1 = (ushort_t*)d_ws;                    // 16*52*512
    ushort_t* W2 = W1 + 425984;                        // 16*32*512
    ushort_t* W3 = W2 + 262144;                        // 16*512

    prep_w<<<dim3(1664), 256, 0, stream>>>(fc1_w, conv_w, fc2_w, out_w, W1, W2, W3);

    // 1024 blocks x 32 rows; 1024 threads (16 waves); 36 KB dynamic LDS;
    // launch_bounds(1024,8): 2 blocks/CU, 8 waves/SIMD; acc=16 AGPR -> ~48 arch VGPRs free
    mega11<<<dim3(1024), 1024, 36864, stream>>>(x, W1, W2, W3, fc1_b, fc2_b, out_b, out);
}

// Round 9
// 220.810 us; speedup vs baseline: 1.1339x; 1.1339x over previous
//
#include <hip/hip_runtime.h>

typedef unsigned short ushort_t;
typedef __attribute__((ext_vector_type(8))) short bf16x8;     // 8 bf16 in 4 VGPRs
typedef __attribute__((ext_vector_type(4))) float f32x4;
typedef __attribute__((ext_vector_type(16))) float f32x16;

__device__ __forceinline__ unsigned short f2bf(float f) {
    union { float f; unsigned u; } v; v.f = f;
    unsigned r = v.u + 0x7FFFu + ((v.u >> 16) & 1u);   // RNE
    return (unsigned short)(r >> 16);
}

// v_cvt_pk_bf16_f32: lo=RNE(a), hi=RNE(b) — bit-identical to f2bf, 1 inst / 2 elems
__device__ __forceinline__ unsigned cvt_pk_bf16(float a, float b) {
    unsigned r;
    asm("v_cvt_pk_bf16_f32 %0, %1, %2" : "=v"(r) : "v"(a), "v"(b));
    return r;
}

// ================= weight prep, fragment-major, coalesced writes =================
// B-fragment layout for v_mfma_f32_32x32x16_bf16: lane = khalf*32 + r32 holds
// W[ngrp*32 + r32][kfrag*16 + khalf*8 .. +8).  Stored as
//   Wf[(ngrp*KFRAGS + kfrag)*512 + lane*8 + e]
// W1eff folds the 3x3 conv into fc1 (p indexes the 28x28 input, zero-padded to 832).
// Conv-fold taps are branch-free: clamped addresses + zeroed weights -> 9 independent loads.
__global__ __launch_bounds__(256) void prep_w(const float* __restrict__ fc1_w,
                                              const float* __restrict__ cw,
                                              const float* __restrict__ fc2_w,
                                              const float* __restrict__ out_w,
                                              ushort_t* __restrict__ W1,
                                              ushort_t* __restrict__ W2,
                                              ushort_t* __restrict__ W3) {
    const int idx = blockIdx.x * 256 + threadIdx.x;
    // ---- W1f: 16 ngrps x 52 kfrags x 512 = 425984 elements ----
    if (idx < 425984) {
        const int ngrp = idx / 26624;              // 52*512
        const int kfrag = (idx % 26624) >> 9;
        const int li = idx & 511;
        const int lane = li >> 3, e = li & 7;
        const int n = ngrp * 32 + (lane & 31);
        const int p = kfrag * 16 + (lane >> 5) * 8 + e;
        float acc = 0.f;
        if (p < 784) {
            const int pr = p / 28, pc = p % 28;
            const float* frow = &fc1_w[n * 676];
#pragma unroll
            for (int dr = 0; dr < 3; ++dr) {
                const int r = pr - dr;
                const bool rok = (unsigned)r < 26u;
                const int rc = rok ? r : 0;
#pragma unroll
                for (int dc = 0; dc < 3; ++dc) {
                    const int c = pc - dc;
                    const bool cok = (unsigned)c < 26u;
                    const int cc = cok ? c : 0;
                    const float w = (rok && cok) ? cw[dr * 3 + dc] : 0.f;
                    acc += w * frow[rc * 26 + cc];     // always-safe address, weight 0 if pad
                }
            }
        }
        W1[idx] = f2bf(acc);
    }
    // ---- W2f: 16 ngrps x 32 kfrags x 512 = 262144 ----
    if (idx < 262144) {
        const int ngrp = idx / 16384;              // 32*512
        const int kfrag = (idx % 16384) >> 9;
        const int li = idx & 511;
        const int lane = li >> 3, e = li & 7;
        const int n = ngrp * 32 + (lane & 31);
        const int p = kfrag * 16 + (lane >> 5) * 8 + e;
        W2[idx] = f2bf(fc2_w[n * 512 + p]);
    }
    if (idx < 16 * 512)  W3[idx] = (idx < 10 * 512) ? f2bf(out_w[idx]) : (ushort_t)0;
}

// ================= fully-fused network, v12: 8-wave blocks, fine-grain occupancy =================
// 1024 blocks x 32 batch rows, 512 threads (8 waves = 2 waves/SIMD granularity).
// Wave w owns a 32x64 tile (n-groups 2w, 2w+1): acc[2] = 32 AGPR; per kfrag 2 W loads +
// ONE shared ds_read_b128 + 2 MFMAs. ~72-80 total regs; launch_bounds(512,6) caps at 85
// (NO spill — the v9-v11 (1024,8) 64-reg bound always spilled 40-56MB) -> 3 blocks/CU,
// 6 waves/SIMD, 75% occupancy. Three independent blocks destagger the per-step barriers;
// 512-thread barrier scope is half of v4-v10's.
// x staging: 4 f32/thread -> 2 packed cvt -> 1 ds_write_b64 (conflict-free).
// LDS: xs0 [32][64] 4KB dbuf (buffer B aliases first 4KB of hs) + hs [32][512] 32KB = 36KB.
__global__ __launch_bounds__(512, 6) void mega12(const float* __restrict__ x,
                                                 const ushort_t* __restrict__ W1,
                                                 const ushort_t* __restrict__ W2,
                                                 const ushort_t* __restrict__ W3,
                                                 const float* __restrict__ b1,
                                                 const float* __restrict__ b2,
                                                 const float* __restrict__ ob,
                                                 float* __restrict__ out) {
    extern __shared__ ushort_t smem[];
    ushort_t* xs0 = smem;                // [32][64]   4 KB  x buffer A (seg-swizzled)
    ushort_t* hs  = smem + 2048;         // [32][512] 32 KB h1/h2 tile; first 4KB = x buffer B

    const int tid = threadIdx.x;
    const int wave = tid >> 6, lane = tid & 63;
    const int r32 = lane & 31, khalf = lane >> 5;
    const int xrow = tid >> 4, xseg = tid & 15;         // x staging: 32 rows x 16 segs(4 cols)
    const int m0 = blockIdx.x * 32;
    const size_t ng0 = wave * 2, ng1 = wave * 2 + 1;    // this wave's two n-groups

    // per-thread staging addresses (loop-invariant)
    const float* xgp = &x[(size_t)(m0 + xrow) * 784 + xseg * 4];
    const int xldso = xrow * 64 + (((xseg >> 1) ^ (xrow & 7)) * 8) + (xseg & 1) * 4;

    f32x16 acc[2];                                      // [j = ngrp]; 32 AGPRs
#pragma unroll
    for (int j = 0; j < 2; ++j)
#pragma unroll
        for (int e = 0; e < 16; ++e) acc[j][e] = 0.f;

    f32x4 xv;                                           // staged x (4 VGPR)
    auto load_x = [&](int ks) {
        const int gc = ks * 64 + xseg * 4;
        if (gc < 784) {
            xv = __builtin_nontemporal_load((const f32x4*)(xgp + ks * 64));
        } else {
            xv = (f32x4){0.f, 0.f, 0.f, 0.f};
        }
    };
    auto write_x = [&](ushort_t* buf) {                 // one ds_write_b64
        const unsigned lo = cvt_pk_bf16(xv.x, xv.y);
        const unsigned hi = cvt_pk_bf16(xv.z, xv.w);
        unsigned* p = (unsigned*)&buf[xldso];
        p[0] = lo; p[1] = hi;
    };

    // h-epilogue: bias+relu -> hs (A-layout, seg' = seg ^ (m&7)); cols = this wave's 64 n
    auto write_h = [&](const float* __restrict__ bias) {
#pragma unroll
        for (int j = 0; j < 2; ++j) {
            const int n = (wave * 2 + j) * 32 + r32;
            const float bb = bias[n];
            const int nseg = n >> 3, nrem = n & 7;
#pragma unroll
            for (int reg = 0; reg < 16; ++reg) {
                const int m = 4 * khalf + (reg & 3) + 8 * (reg >> 2);      // 0..31
                hs[m * 512 + ((nseg ^ (m & 7)) * 8) + nrem] = f2bf(fmaxf(acc[j][reg] + bb, 0.f));
            }
        }
    };

    // one phase-1 K-subtile: 2 W loads + 1 shared A ds_read + 2 MFMAs
    auto p1_ksub = [&](int kf, int ksub, const ushort_t* bufp) {
        const bf16x8 bw0 = *(const bf16x8*)&W1[(ng0 * 52 + kf) * 512 + lane * 8];
        const bf16x8 bw1 = *(const bf16x8*)&W1[(ng1 * 52 + kf) * 512 + lane * 8];
        const int q = 2 * ksub + khalf;
        const bf16x8 af = *(const bf16x8*)&bufp[r32 * 64 + ((q ^ (r32 & 7)) * 8)];
        __builtin_amdgcn_s_setprio(1);
        acc[0] = __builtin_amdgcn_mfma_f32_32x32x16_bf16(af, bw0, acc[0], 0, 0, 0);
        acc[1] = __builtin_amdgcn_mfma_f32_32x32x16_bf16(af, bw1, acc[1], 0, 0, 0);
        __builtin_amdgcn_s_setprio(0);
    };

    load_x(0);
    write_x(xs0);
    __syncthreads();

    // ---------------- phase 1: K = 832, 12 full steps of BK=64, 1 barrier/step ----------------
    for (int ks = 0; ks < 12; ++ks) {
        load_x(ks + 1);                                 // next x flies under the step
        const ushort_t* bufp = (ks & 1) ? hs : xs0;
        p1_ksub(ks * 4 + 0, 0, bufp);
        p1_ksub(ks * 4 + 1, 1, bufp);
        p1_ksub(ks * 4 + 2, 2, bufp);
        p1_ksub(ks * 4 + 3, 3, bufp);
        write_x((ks & 1) ? xs0 : hs);                   // fill the other buffer
        __syncthreads();
    }
    // ---- step 12: only kfrag 48 is nonzero (k 768..783 real; 784..831 is zero pad) ----
    p1_ksub(48, 0, xs0);                                // ks=12 even -> buffer A
    // no barrier needed: step-12 read xs0 only; h1 writes touch hs, whose last readers
    // (step 11 x-alias reads) finished before the ks=11 barrier.

    // ---- h1 = relu(acc + b1) -> hs ----
    write_h(b1);
#pragma unroll
    for (int j = 0; j < 2; ++j)
#pragma unroll
        for (int e = 0; e < 16; ++e) acc[j][e] = 0.f;
    __syncthreads();

    // ---------------- phase 2: K = 512, 8 steps, no intra-phase barriers ----------------
    for (int ks = 0; ks < 8; ++ks) {
#pragma unroll
        for (int ksub = 0; ksub < 4; ++ksub) {
            const int kf = ks * 4 + ksub;
            const bf16x8 bw0 = *(const bf16x8*)&W2[(ng0 * 32 + kf) * 512 + lane * 8];
            const bf16x8 bw1 = *(const bf16x8*)&W2[(ng1 * 32 + kf) * 512 + lane * 8];
            const int hq = kf * 2 + khalf;              // 16B-seg index within hs row (0..63)
            const bf16x8 af = *(const bf16x8*)&hs[r32 * 512 + ((hq ^ (r32 & 7)) * 8)];
            __builtin_amdgcn_s_setprio(1);
            acc[0] = __builtin_amdgcn_mfma_f32_32x32x16_bf16(af, bw0, acc[0], 0, 0, 0);
            acc[1] = __builtin_amdgcn_mfma_f32_32x32x16_bf16(af, bw1, acc[1], 0, 0, 0);
            __builtin_amdgcn_s_setprio(0);
        }
    }
    __syncthreads();                                    // all hs(h1) reads done

    // ---- h2 = relu(acc + b2) -> hs ----
    write_h(b2);
    __syncthreads();

    // ---------------- head: waves 0..1 -> 16 rows each, K=512, direct stores ----------------
    if (wave < 2) {
        const int quad = lane >> 4, l16 = lane & 15;
        const int row = wave * 16 + l16;
        f32x4 hacc = {0.f, 0.f, 0.f, 0.f};
#pragma unroll
        for (int ks = 0; ks < 16; ++ks) {
            const int seg = 4 * ks + quad;
            const bf16x8 a = *(const bf16x8*)&hs[row * 512 + ((seg ^ (row & 7)) * 8)];
            const bf16x8 b = *(const bf16x8*)&W3[l16 * 512 + ks * 32 + quad * 8];
            hacc = __builtin_amdgcn_mfma_f32_16x16x32_bf16(a, b, hacc, 0, 0, 0);
        }
        if (l16 < 10) {
            const float bb = ob[l16];
#pragma unroll
            for (int r = 0; r < 4; ++r)
                out[(size_t)(m0 + wave * 16 + quad * 4 + r) * 10 + l16] = hacc[r] + bb;
        }
    }
}

extern "C" void kernel_launch(void* const* d_in, const int* in_sizes, int n_in,
                              void* d_out, int out_size, void* d_ws, size_t ws_size,
                              hipStream_t stream) {
    const float* x      = (const float*)d_in[0];
    const float* conv_w = (const float*)d_in[1];
    const float* fc1_w  = (const float*)d_in[2];
    const float* fc1_b  = (const float*)d_in[3];
    const float* fc2_w  = (const float*)d_in[4];
    const float* fc2_b  = (const float*)d_in[5];
    const float* out_w  = (const float*)d_in[6];
    const float* out_b  = (const float*)d_in[7];
    float* out = (float*)d_out;

    // workspace: W1f | W2f | W3 (≈1.4 MB total), fragment-major layouts
    ushort_t* W1 = (ushort_t*)d_ws;                    // 16*52*512
    ushort_t* W2 = W1 + 425984;                        // 16*32*512
    ushort_t* W3 = W2 + 262144;                        // 16*512

    prep_w<<<dim3(1664), 256, 0, stream>>>(fc1_w, conv_w, fc2_w, out_w, W1, W2, W3);

    // 1024 blocks x 32 rows; 512 threads (8 waves); 36 KB dynamic LDS;
    // launch_bounds(512,6): <=85 regs (no spill), 3 blocks/CU, 6 waves/SIMD
    mega12<<<dim3(1024), 512, 36864, stream>>>(x, W1, W2, W3, fc1_b, fc2_b, out_b, out);
}

// Round 10
// 214.786 us; speedup vs baseline: 1.1657x; 1.0280x over previous
//
#include <hip/hip_runtime.h>

typedef unsigned short ushort_t;
typedef __attribute__((ext_vector_type(8))) short bf16x8;     // 8 bf16 in 4 VGPRs
typedef __attribute__((ext_vector_type(4))) float f32x4;
typedef __attribute__((ext_vector_type(16))) float f32x16;

__device__ __forceinline__ unsigned short f2bf(float f) {
    union { float f; unsigned u; } v; v.f = f;
    unsigned r = v.u + 0x7FFFu + ((v.u >> 16) & 1u);   // RNE
    return (unsigned short)(r >> 16);
}

// v_cvt_pk_bf16_f32: lo=RNE(a), hi=RNE(b) — bit-identical to f2bf, 1 inst / 2 elems
__device__ __forceinline__ unsigned cvt_pk_bf16(float a, float b) {
    unsigned r;
    asm("v_cvt_pk_bf16_f32 %0, %1, %2" : "=v"(r) : "v"(a), "v"(b));
    return r;
}

// ================= weight prep, fragment-major, coalesced writes =================
// B-fragment layout for v_mfma_f32_32x32x16_bf16: lane = khalf*32 + r32 holds
// W[ngrp*32 + r32][kfrag*16 + khalf*8 .. +8).  Stored as
//   Wf[(ngrp*KFRAGS + kfrag)*512 + lane*8 + e]
// W1eff folds the 3x3 conv into fc1 (p indexes the 28x28 input, zero-padded to 832).
__global__ __launch_bounds__(256) void prep_w(const float* __restrict__ fc1_w,
                                              const float* __restrict__ cw,
                                              const float* __restrict__ fc2_w,
                                              const float* __restrict__ out_w,
                                              ushort_t* __restrict__ W1,
                                              ushort_t* __restrict__ W2,
                                              ushort_t* __restrict__ W3) {
    const int idx = blockIdx.x * 256 + threadIdx.x;
    // ---- W1f: 16 ngrps x 52 kfrags x 512 = 425984 elements ----
    if (idx < 425984) {
        const int ngrp = idx / 26624;              // 52*512
        const int kfrag = (idx % 26624) >> 9;
        const int li = idx & 511;
        const int lane = li >> 3, e = li & 7;
        const int n = ngrp * 32 + (lane & 31);
        const int p = kfrag * 16 + (lane >> 5) * 8 + e;
        float acc = 0.f;
        if (p < 784) {
            const int pr = p / 28, pc = p % 28;
            const float* frow = &fc1_w[n * 676];
#pragma unroll
            for (int dr = 0; dr < 3; ++dr) {
                const int r = pr - dr;
                const bool rok = (unsigned)r < 26u;
                const int rc = rok ? r : 0;
#pragma unroll
                for (int dc = 0; dc < 3; ++dc) {
                    const int c = pc - dc;
                    const bool cok = (unsigned)c < 26u;
                    const int cc = cok ? c : 0;
                    const float w = (rok && cok) ? cw[dr * 3 + dc] : 0.f;
                    acc += w * frow[rc * 26 + cc];     // always-safe address, weight 0 if pad
                }
            }
        }
        W1[idx] = f2bf(acc);
    }
    // ---- W2f: 16 ngrps x 32 kfrags x 512 = 262144 ----
    if (idx < 262144) {
        const int ngrp = idx / 16384;              // 32*512
        const int kfrag = (idx % 16384) >> 9;
        const int li = idx & 511;
        const int lane = li >> 3, e = li & 7;
        const int n = ngrp * 32 + (lane & 31);
        const int p = kfrag * 16 + (lane >> 5) * 8 + e;
        W2[idx] = f2bf(fc2_w[n * 512 + p]);
    }
    if (idx < 16 * 512)  W3[idx] = (idx < 10 * 512) ? f2bf(out_w[idx]) : (ushort_t)0;
}

// ================= fully-fused network, v13: v5 + explicit W software pipeline =================
// 512 blocks x 64 batch rows, 512 threads (8 waves), launch_bounds(512,4): 128 regs/wave,
// 2 blocks/CU (72KB LDS), 4 waves/SIMD. Wave w owns 64x64 (n-groups 2w,2w+1):
// acc[2][2] = 64 AGPR (forced by M=64 fusion).
// NEW: hand-rotated 1-kfrag-deep W prefetch (bwc/bwn). Each iteration issues kfrag k+1's
// two W loads BEFORE the MFMAs consuming kfrag k's — the consuming wait becomes
// s_waitcnt vmcnt(2) on loads issued ~400cy earlier (4-wave TLP cadence), taking the
// W L2 latency OFF the MFMA critical path. The pipeline crosses the phase1->phase2
// boundary. The compiler provably never does this on its own (v6/v8/v12).
__global__ __launch_bounds__(512, 4) void mega13(const float* __restrict__ x,
                                                 const ushort_t* __restrict__ W1,
                                                 const ushort_t* __restrict__ W2,
                                                 const ushort_t* __restrict__ W3,
                                                 const float* __restrict__ b1,
                                                 const float* __restrict__ b2,
                                                 const float* __restrict__ ob,
                                                 float* __restrict__ out) {
    extern __shared__ ushort_t smem[];
    ushort_t* xs0 = smem;                // [64][64]   8 KB  x buffer A (seg-swizzled)
    ushort_t* hs  = smem + 4096;         // [64][512] 64 KB h1/h2 tile; first 8KB = x buffer B

    const int tid = threadIdx.x;
    const int wave = tid >> 6, lane = tid & 63;
    const int r32 = lane & 31, khalf = lane >> 5;
    const int xrow = tid >> 3, xoct = tid & 7;          // x staging: 64 rows x 8 octs
    const int m0 = blockIdx.x * 64;
    const size_t ng0 = wave * 2, ng1 = wave * 2 + 1;    // this wave's two n-groups

    // W fragment base pointers (per-lane, loop-invariant)
    const ushort_t* w1p0 = &W1[ng0 * 52 * 512 + lane * 8];
    const ushort_t* w1p1 = &W1[ng1 * 52 * 512 + lane * 8];
    const ushort_t* w2p0 = &W2[ng0 * 32 * 512 + lane * 8];
    const ushort_t* w2p1 = &W2[ng1 * 32 * 512 + lane * 8];

    f32x16 acc[2][2];                                   // [i = m-frag][j = ngrp]; 64 AGPR
#pragma unroll
    for (int a = 0; a < 2; ++a)
#pragma unroll
        for (int j = 0; j < 2; ++j)
#pragma unroll
            for (int e = 0; e < 16; ++e) acc[a][j][e] = 0.f;

    // ---- x prefetch (nontemporal fp32), one K-step ahead; 1 row-segment / thread ----
    f32x4 xv0, xv1;
    auto load_x = [&](int ks) {
        const int gc = ks * 64 + xoct * 8;
        if (gc < 784) {
            const f32x4* p = (const f32x4*)&x[(size_t)(m0 + xrow) * 784 + gc];
            xv0 = __builtin_nontemporal_load(p);
            xv1 = __builtin_nontemporal_load(p + 1);
        } else {
            xv0 = (f32x4){0.f, 0.f, 0.f, 0.f};
            xv1 = (f32x4){0.f, 0.f, 0.f, 0.f};
        }
    };
    auto store_x = [&](ushort_t* buf) {
        union { bf16x8 h; unsigned u[4]; } a, b;
        a.u[0] = cvt_pk_bf16(xv0.x, xv0.y); a.u[1] = cvt_pk_bf16(xv0.z, xv0.w);
        a.u[2] = cvt_pk_bf16(xv1.x, xv1.y); a.u[3] = cvt_pk_bf16(xv1.z, xv1.w);
        (void)b;
        *(bf16x8*)&buf[xrow * 64 + ((xoct ^ (xrow & 7)) * 8)] = a.h;
    };

    // h-epilogue: bias+relu -> hs (A-layout, seg' = seg ^ (m&7)); cols = this wave's 64 n
    auto write_h = [&](const float* __restrict__ bias) {
#pragma unroll
        for (int j = 0; j < 2; ++j) {
            const int n = (wave * 2 + j) * 32 + r32;
            const float bb = bias[n];
            const int nseg = n >> 3, nrem = n & 7;
#pragma unroll
            for (int i = 0; i < 2; ++i)
#pragma unroll
                for (int reg = 0; reg < 16; ++reg) {
                    const int m = i * 32 + 4 * khalf + (reg & 3) + 8 * (reg >> 2);
                    hs[m * 512 + ((nseg ^ (m & 7)) * 8) + nrem] = f2bf(fmaxf(acc[i][j][reg] + bb, 0.f));
                }
        }
    };

    load_x(0);
    store_x(xs0);
    __syncthreads();

    // ---- W pipeline registers: bwc = current kfrag's fragments, loaded one kfrag early ----
    bf16x8 bwc0 = *(const bf16x8*)(w1p0);               // kfrag 0
    bf16x8 bwc1 = *(const bf16x8*)(w1p1);

    // ---------------- phase 1: K = 832, kfrags 0..48 (49..51 zero pad skipped) ----------------
    for (int ks = 0; ks < 12; ++ks) {
        load_x(ks + 1);                                 // next x flies under the MFMAs
        const ushort_t* bufp = (ks & 1) ? hs : xs0;
#pragma unroll
        for (int ksub = 0; ksub < 4; ++ksub) {
            const int kf = ks * 4 + ksub;
            // issue NEXT kfrag's W loads before this kfrag's MFMAs (1-deep pipeline)
            bf16x8 bwn0, bwn1;
            if (kf < 48) {
                bwn0 = *(const bf16x8*)(w1p0 + (kf + 1) * 512);
                bwn1 = *(const bf16x8*)(w1p1 + (kf + 1) * 512);
            } else {                                    // cross-phase: prefetch W2 kfrag 0
                bwn0 = *(const bf16x8*)(w2p0);
                bwn1 = *(const bf16x8*)(w2p1);
            }
            const int q = 2 * ksub + khalf;
            bf16x8 af[2];
#pragma unroll
            for (int i = 0; i < 2; ++i) {
                const int m = i * 32 + r32;
                af[i] = *(const bf16x8*)&bufp[m * 64 + ((q ^ (m & 7)) * 8)];
            }
            __builtin_amdgcn_s_setprio(1);
            acc[0][0] = __builtin_amdgcn_mfma_f32_32x32x16_bf16(af[0], bwc0, acc[0][0], 0, 0, 0);
            acc[0][1] = __builtin_amdgcn_mfma_f32_32x32x16_bf16(af[0], bwc1, acc[0][1], 0, 0, 0);
            acc[1][0] = __builtin_amdgcn_mfma_f32_32x32x16_bf16(af[1], bwc0, acc[1][0], 0, 0, 0);
            acc[1][1] = __builtin_amdgcn_mfma_f32_32x32x16_bf16(af[1], bwc1, acc[1][1], 0, 0, 0);
            __builtin_amdgcn_s_setprio(0);
            bwc0 = bwn0; bwc1 = bwn1;
        }
        store_x((ks & 1) ? xs0 : hs);                   // fill the other buffer
        __syncthreads();
    }
    // ---- kfrag 48 (cols 768..783 real); bwc holds it? No: bwc now holds kfrag 48 ----
    {
        const ushort_t* bufp = xs0;                     // ks=12 even -> buffer A
        // bwc currently holds kfrag 48 (loaded during ksub 3 of ks=11? No: rotation).
        // After the ks=11 step, bwc holds kfrag 48's fragments (loaded at kf=47 iter).
        bf16x8 bwn0 = *(const bf16x8*)(w2p0);           // prefetch phase-2 kfrag 0
        bf16x8 bwn1 = *(const bf16x8*)(w2p1);
        const int q = khalf;
        bf16x8 af[2];
#pragma unroll
        for (int i = 0; i < 2; ++i) {
            const int m = i * 32 + r32;
            af[i] = *(const bf16x8*)&bufp[m * 64 + ((q ^ (m & 7)) * 8)];
        }
        __builtin_amdgcn_s_setprio(1);
        acc[0][0] = __builtin_amdgcn_mfma_f32_32x32x16_bf16(af[0], bwc0, acc[0][0], 0, 0, 0);
        acc[0][1] = __builtin_amdgcn_mfma_f32_32x32x16_bf16(af[0], bwc1, acc[0][1], 0, 0, 0);
        acc[1][0] = __builtin_amdgcn_mfma_f32_32x32x16_bf16(af[1], bwc0, acc[1][0], 0, 0, 0);
        acc[1][1] = __builtin_amdgcn_mfma_f32_32x32x16_bf16(af[1], bwc1, acc[1][1], 0, 0, 0);
        __builtin_amdgcn_s_setprio(0);
        bwc0 = bwn0; bwc1 = bwn1;                       // now holds W2 kfrag 0
    }

    // ---- h1 = relu(acc + b1) -> hs ----
    write_h(b1);
#pragma unroll
    for (int a = 0; a < 2; ++a)
#pragma unroll
        for (int j = 0; j < 2; ++j)
#pragma unroll
            for (int e = 0; e < 16; ++e) acc[a][j][e] = 0.f;
    __syncthreads();

    // ---------------- phase 2: K = 512, kfrags 0..31, no barriers, same pipeline ----------------
    for (int ks = 0; ks < 8; ++ks) {
#pragma unroll
        for (int ksub = 0; ksub < 4; ++ksub) {
            const int kf = ks * 4 + ksub;
            bf16x8 bwn0, bwn1;
            if (kf < 31) {
                bwn0 = *(const bf16x8*)(w2p0 + (kf + 1) * 512);
                bwn1 = *(const bf16x8*)(w2p1 + (kf + 1) * 512);
            }
            const int hq = kf * 2 + khalf;              // 16B-seg index within hs row (0..63)
            bf16x8 af[2];
#pragma unroll
            for (int i = 0; i < 2; ++i) {
                const int m = i * 32 + r32;
                af[i] = *(const bf16x8*)&hs[m * 512 + ((hq ^ (m & 7)) * 8)];
            }
            __builtin_amdgcn_s_setprio(1);
            acc[0][0] = __builtin_amdgcn_mfma_f32_32x32x16_bf16(af[0], bwc0, acc[0][0], 0, 0, 0);
            acc[0][1] = __builtin_amdgcn_mfma_f32_32x32x16_bf16(af[0], bwc1, acc[0][1], 0, 0, 0);
            acc[1][0] = __builtin_amdgcn_mfma_f32_32x32x16_bf16(af[1], bwc0, acc[1][0], 0, 0, 0);
            acc[1][1] = __builtin_amdgcn_mfma_f32_32x32x16_bf16(af[1], bwc1, acc[1][1], 0, 0, 0);
            __builtin_amdgcn_s_setprio(0);
            if (kf < 31) { bwc0 = bwn0; bwc1 = bwn1; }
        }
    }
    __syncthreads();                                    // all hs(h1) reads done

    // ---- h2 = relu(acc + b2) -> hs ----
    write_h(b2);
    __syncthreads();

    // ---------------- head: waves 0..3 -> 16 rows each, K=512, direct stores ----------------
    if (wave < 4) {
        const int quad = lane >> 4, l16 = lane & 15;
        const int row = wave * 16 + l16;
        f32x4 hacc = {0.f, 0.f, 0.f, 0.f};
#pragma unroll
        for (int ks = 0; ks < 16; ++ks) {
            const int seg = 4 * ks + quad;
            const bf16x8 a = *(const bf16x8*)&hs[row * 512 + ((seg ^ (row & 7)) * 8)];
            const bf16x8 b = *(const bf16x8*)&W3[l16 * 512 + ks * 32 + quad * 8];
            hacc = __builtin_amdgcn_mfma_f32_16x16x32_bf16(a, b, hacc, 0, 0, 0);
        }
        if (l16 < 10) {
            const float bb = ob[l16];
#pragma unroll
            for (int r = 0; r < 4; ++r)
                out[(size_t)(m0 + wave * 16 + quad * 4 + r) * 10 + l16] = hacc[r] + bb;
        }
    }
}

extern "C" void kernel_launch(void* const* d_in, const int* in_sizes, int n_in,
                              void* d_out, int out_size, void* d_ws, size_t ws_size,
                              hipStream_t stream) {
    const float* x      = (const float*)d_in[0];
    const float* conv_w = (const float*)d_in[1];
    const float* fc1_w  = (const float*)d_in[2];
    const float* fc1_b  = (const float*)d_in[3];
    const float* fc2_w  = (const float*)d_in[4];
    const float* fc2_b  = (const float*)d_in[5];
    const float* out_w  = (const float*)d_in[6];
    const float* out_b  = (const float*)d_in[7];
    float* out = (float*)d_out;

    // workspace: W1f | W2f | W3 (≈1.4 MB total), fragment-major layouts
    ushort_t* W1 = (ushort_t*)d_ws;                    // 16*52*512
    ushort_t* W2 = W1 + 425984;                        // 16*32*512
    ushort_t* W3 = W2 + 262144;                        // 16*512

    prep_w<<<dim3(1664), 256, 0, stream>>>(fc1_w, conv_w, fc2_w, out_w, W1, W2, W3);

    // 512 blocks x 64 rows; 512 threads (8 waves); 72 KB dynamic LDS;
    // launch_bounds(512,4): 128 regs/wave, 2 blocks/CU, explicit W software pipeline
    mega13<<<dim3(512), 512, 73728, stream>>>(x, W1, W2, W3, fc1_b, fc2_b, out_b, out);
}